// Round 9
// baseline (113.670 us; speedup 1.0000x reference)
//
#include <hip/hip_runtime.h>

// x: [8, 32, 32, 32, 32] fp32.  Flat = b*2^20 + i*32768 + j*1024 + k*32 + c
// W: [32, 256] row-major (o, 8 sections). Sections:
//   0:x 1:mean_i 2:mean_j 3:mean_k 4:mean_ij 5:mean_ik 6:mean_jk 7:mean_ijk
// out[b,i,j,k,o] = W0.x + B1[b,j,k,o] + B2[b,i,k,o] + A3[b,i,j,o]
//                + A12[b,k,o] + A13[b,j,o] + A23[b,i,o] + A123[b,o] + bias[o]
// R15: overlap restructure. final's GEMM half (P = x*W0 + bias) depends on
// NOTHING from reduce/mid -> run it concurrently with reduce in ONE kernel
// (blocks 0..511 reduce, 512..2559 GEMM; independent, no sync needed).
// Then mid (tables), then a pure-streaming epilogue out = P + 7 tables.
// Costs a P round-trip (+67MB ~ +11us BW) but removes reduce (~16-20us)
// from the serialized critical path and makes the last kernel BW-shaped.
// Bodies verbatim from verified R4/R10 kernels. Fill (~42us re-poison) is
// a fixed harness cost; kernels were ~65us vs ~24us BW floor.

static __device__ __forceinline__ float4 f4add(float4 a, float4 b) {
  a.x += b.x; a.y += b.y; a.z += b.z; a.w += b.w; return a;
}

// blocks 0..255: seg0 reduce -> S1. 256..511: segA -> S2,S3 (R10 verbatim).
// blocks 512..2559: staged GEMM tile (128 rows): P = x*W0^T + bias.
__global__ __launch_bounds__(256) void front_kernel(
    const float* __restrict__ x, const float* __restrict__ W,
    const float* __restrict__ bias,
    float* __restrict__ S1, float* __restrict__ S2, float* __restrict__ S3,
    float* __restrict__ P) {
  __shared__ float smem[8224];   // segA: [8][1028]=8224. GEMM: 4224+1024=5248.
  const int t = threadIdx.x;
  const int bid = blockIdx.x;

  if (bid < 256) {
    // seg0: S1[b, j=a, k, c] = sum_i x[b,i,a,k,c]
    const int b = bid >> 5, a = bid & 31;
    const float* base = x + ((size_t)b << 20) + a * 1024 + 4 * t;
    float4 acc = make_float4(0.f, 0.f, 0.f, 0.f);
    #pragma unroll
    for (int i = 0; i < 32; ++i) acc = f4add(acc, *(const float4*)(base + i * 32768));
    ((float4*)(S1 + (size_t)(b * 32 + a) * 1024))[t] = acc;
  } else if (bid < 512) {
    // segA: block (b, i=a): stream slab x[b,a,:,:,:] once -> S2 row + S3 row
    float* sT = smem;                        // [8][1028]
    const int idx = bid - 256;
    const int b = idx >> 5, a = idx & 31;
    const float* slab = x + ((size_t)b << 20) + a * 32768;
    float4 accS2 = make_float4(0.f, 0.f, 0.f, 0.f);
    const int jl = t >> 5, cc = t & 31;      // S3 role: (j_loc, c)
    float* s3row = S3 + (size_t)(b * 32 + a) * 1024;

    for (int jt = 0; jt < 4; ++jt) {
      const float4* src4 = (const float4*)(slab + jt * 8192);
      #pragma unroll
      for (int m = 0; m < 8; ++m) {
        const int q = t + 256 * m;           // float4 idx in tile
        const float4 v = src4[q];
        float* p = sT + (q >> 8) * 1028 + 4 * (q & 255);
        p[0] = v.x; p[1] = v.y; p[2] = v.z; p[3] = v.w;
      }
      __syncthreads();
      #pragma unroll
      for (int j = 0; j < 8; ++j)
        accS2 = f4add(accS2, *(const float4*)(sT + j * 1028 + 4 * t));
      float s3 = 0.f;
      #pragma unroll
      for (int k = 0; k < 32; ++k) s3 += sT[jl * 1028 + k * 32 + cc];
      s3row[jt * 256 + t] = s3;              // j = 8*jt + jl, coalesced
      __syncthreads();
    }
    ((float4*)(S2 + (size_t)(b * 32 + a) * 1024))[t] = accS2;
  } else {
    // GEMM tile: P[row, o] = sum_c x[row, c] * W0t[c][o] + bias[o]
    float* xs = smem;            // [128][33]
    float* wt = smem + 4224;     // W0 transposed [c*32+o]
    const int tile = bid - 512;
    const size_t pos0 = (size_t)tile * 128;

    const int rg = t >> 3, og = t & 7;
    const int lrow0 = 4 * rg;
    const size_t p0 = pos0 + lrow0;
    const int oo = og * 4;

    const float4 vbi = *(const float4*)(bias + oo);

    const float4* xp4 = (const float4*)(x + pos0 * 32);
    #pragma unroll
    for (int m = 0; m < 4; ++m) {
      const int q = t + 256 * m;
      const float4 v = xp4[q];
      float* p = xs + (q >> 3) * 33 + 4 * (q & 7);
      p[0] = v.x; p[1] = v.y; p[2] = v.z; p[3] = v.w;
    }
    #pragma unroll
    for (int m = 0; m < 4; ++m) {
      const int e = t + 256 * m;
      wt[e] = W[(e & 31) * 256 + (e >> 5)];  // W0t[c*32+o]
    }
    __syncthreads();

    float acc[4][4];
    #pragma unroll
    for (int r = 0; r < 4; ++r)
      #pragma unroll
      for (int u = 0; u < 4; ++u) acc[r][u] = 0.f;

    const float4* wt4 = (const float4*)wt;
    #pragma unroll
    for (int c = 0; c < 32; ++c) {
      const float4 w = wt4[c * 8 + og];
      #pragma unroll
      for (int r = 0; r < 4; ++r) {
        const float xv = xs[(lrow0 + r) * 33 + c];
        acc[r][0] += xv * w.x; acc[r][1] += xv * w.y;
        acc[r][2] += xv * w.z; acc[r][3] += xv * w.w;
      }
    }

    #pragma unroll
    for (int r = 0; r < 4; ++r) {
      *(float4*)(P + (p0 + r) * 32 + oo) =
          make_float4(acc[r][0] + vbi.x, acc[r][1] + vbi.y,
                      acc[r][2] + vbi.z, acc[r][3] + vbi.w);
    }
  }
}

// Merged: blocks 0..95 = three [8192x32]x[32x32] GEMMs (B1,B2,A3, scaled 1/32);
//         blocks 96..119 = second-level pools -> A12/A13/A23/A123 tables.
__global__ __launch_bounds__(256) void mid_kernel(
    const float* __restrict__ S1, const float* __restrict__ S2,
    const float* __restrict__ S3, const float* __restrict__ W,
    float* __restrict__ B1, float* __restrict__ B2, float* __restrict__ A3o,
    float* __restrict__ A12g, float* __restrict__ A13g,
    float* __restrict__ A23g, float* __restrict__ A123g) {
  __shared__ float smem[9472];
  const int t = threadIdx.x;
  if (blockIdx.x < 96) {
    float* xs = smem;            // [256][33]
    float* wt = smem + 8448;     // W section seg+1 transposed [c*32+o]
    const int seg = blockIdx.x >> 5;
    const int r0 = (blockIdx.x & 31) * 256;
    const float* src = (seg == 0) ? S1 : (seg == 1) ? S2 : S3;
    float* dst = (seg == 0) ? B1 : (seg == 1) ? B2 : A3o;

    const float4* sp4 = (const float4*)(src + (size_t)r0 * 32);
    #pragma unroll
    for (int m = 0; m < 8; ++m) {
      const int q = t + 256 * m;
      const float4 v = sp4[q];
      float* p = xs + (q >> 3) * 33 + 4 * (q & 7);
      p[0] = v.x; p[1] = v.y; p[2] = v.z; p[3] = v.w;
    }
    #pragma unroll
    for (int m = 0; m < 4; ++m) {
      const int e = t + 256 * m;
      wt[e] = W[(e & 31) * 256 + (seg + 1) * 32 + (e >> 5)];
    }
    __syncthreads();

    float acc[32];
    #pragma unroll
    for (int o = 0; o < 32; ++o) acc[o] = 0.f;
    const float4* wt4 = (const float4*)wt;
    #pragma unroll
    for (int c = 0; c < 32; ++c) {
      const float xv = xs[t * 33 + c];
      #pragma unroll
      for (int o4 = 0; o4 < 8; ++o4) {
        const float4 w = wt4[c * 8 + o4];
        acc[o4 * 4 + 0] += xv * w.x;
        acc[o4 * 4 + 1] += xv * w.y;
        acc[o4 * 4 + 2] += xv * w.z;
        acc[o4 * 4 + 3] += xv * w.w;
      }
    }
    __syncthreads();
    #pragma unroll
    for (int o = 0; o < 32; ++o) xs[t * 33 + o] = acc[o] * (1.f / 32.f);
    __syncthreads();
    float* op = dst + (size_t)r0 * 32;
    #pragma unroll
    for (int m = 0; m < 32; ++m) {
      const int f = t + 256 * m;
      op[f] = xs[(f >> 5) * 33 + (f & 31)];
    }
  } else {
    // pool: blk = seg*8 + b
    const int blk = blockIdx.x - 96;
    const int seg = blk >> 3, b = blk & 7;
    float* sBuf  = smem;          // [32][32] second-level sums
    float* sW    = smem + 1024;   // section 4+seg transposed [c*32+o]
    float* sW7   = smem + 2048;   // section 7 transposed
    float* sS123 = smem + 3072;   // [32]
    const int sec = 4 + seg;

    #pragma unroll
    for (int m = 0; m < 4; ++m) {
      const int e = t + 256 * m, c = e >> 5, o = e & 31;
      sW[e] = W[o * 256 + sec * 32 + c];
      if (seg == 0) sW7[e] = W[o * 256 + 7 * 32 + c];
    }
    const float* Sb = ((seg == 2) ? S2 : S1) + (size_t)b * 32768;
    #pragma unroll
    for (int m = 0; m < 4; ++m) {
      const int e = t + 256 * m, a = e >> 5, c = e & 31;
      float s = 0.f;
      if (seg == 0) {            // S12[k=a,c] = sum_j S1[b,j,a,c]
        for (int j = 0; j < 32; ++j) s += Sb[j * 1024 + a * 32 + c];
      } else {                   // S13/S23[(j|i)=a,c] = sum_k
        for (int k = 0; k < 32; ++k) s += Sb[a * 1024 + k * 32 + c];
      }
      sBuf[e] = s;
    }
    __syncthreads();
    if (seg == 0 && t < 32) {
      float s = 0.f;
      for (int k = 0; k < 32; ++k) s += sBuf[k * 32 + t];
      sS123[t] = s;
    }
    __syncthreads();
    float* Ag = (seg == 0) ? A12g : (seg == 1) ? A13g : A23g;
    #pragma unroll
    for (int m = 0; m < 4; ++m) {
      const int e = t + 256 * m, a = e >> 5, o = e & 31;
      float s = 0.f;
      #pragma unroll
      for (int c = 0; c < 32; ++c) s += sW[c * 32 + o] * sBuf[a * 32 + c];
      Ag[b * 1024 + e] = s * (1.f / 1024.f);
    }
    if (seg == 0 && t < 32) {
      float s = 0.f;
      #pragma unroll
      for (int c = 0; c < 32; ++c) s += sW7[c * 32 + t] * sS123[c];
      A123g[b * 32 + t] = s * (1.f / 32768.f);
    }
  }
}

// Epilogue: out = P + B1 + B2 + A3 + A12 + A13 + A23 + A123. Pure stream,
// no LDS, no sync. 2048 blocks x 256 threads; thread = (rg: 4 rows, og: f4).
__global__ __launch_bounds__(256) void back_kernel(
    const float* __restrict__ P, const float* __restrict__ B1,
    const float* __restrict__ B2, const float* __restrict__ A3o,
    const float* __restrict__ A12g, const float* __restrict__ A13g,
    const float* __restrict__ A23g, const float* __restrict__ A123g,
    float* __restrict__ out) {
  const int t = threadIdx.x;
  const size_t pos0 = (size_t)blockIdx.x * 128;
  const int rg = t >> 3, og = t & 7;
  const int lrow0 = 4 * rg;
  const size_t p0 = pos0 + lrow0;
  const int k0 = (int)(p0 & 31), j = (int)(p0 >> 5) & 31,
            i = (int)(p0 >> 10) & 31, b = (int)(p0 >> 15);
  const int oo = og * 4;

  const float4 va3  = *(const float4*)(A3o  + ((size_t)((b * 32 + i) * 32 + j)) * 32 + oo);
  const float4 va13 = *(const float4*)(A13g + (size_t)(b * 32 + j) * 32 + oo);
  const float4 va23 = *(const float4*)(A23g + (size_t)(b * 32 + i) * 32 + oo);
  const float4 va123= *(const float4*)(A123g + (size_t)b * 32 + oo);
  float inv[4];
  inv[0] = va3.x + va13.x + va23.x + va123.x;
  inv[1] = va3.y + va13.y + va23.y + va123.y;
  inv[2] = va3.z + va13.z + va23.z + va123.z;
  inv[3] = va3.w + va13.w + va23.w + va123.w;

  #pragma unroll
  for (int r = 0; r < 4; ++r) {
    const int k = k0 + r;
    const float4 vp  = *(const float4*)(P  + (p0 + r) * 32 + oo);
    const float4 vb1 = *(const float4*)(B1 + ((size_t)((b * 32 + j) * 32 + k)) * 32 + oo);
    const float4 vb2 = *(const float4*)(B2 + ((size_t)((b * 32 + i) * 32 + k)) * 32 + oo);
    const float4 v12 = *(const float4*)(A12g + (size_t)(b * 32 + k) * 32 + oo);
    *(float4*)(out + (p0 + r) * 32 + oo) = make_float4(
        vp.x + inv[0] + vb1.x + vb2.x + v12.x,
        vp.y + inv[1] + vb1.y + vb2.y + v12.y,
        vp.z + inv[2] + vb1.z + vb2.z + v12.z,
        vp.w + inv[3] + vb1.w + vb2.w + v12.w);
  }
}

extern "C" void kernel_launch(void* const* d_in, const int* in_sizes, int n_in,
                              void* d_out, int out_size, void* d_ws, size_t ws_size,
                              hipStream_t stream) {
  const float* x    = (const float*)d_in[0];
  const float* W    = (const float*)d_in[1];
  const float* bias = (const float*)d_in[2];
  float* out = (float*)d_out;
  float* ws  = (float*)d_ws;
  float* S1    = ws;                 // 262144 each
  float* S2    = ws + 262144;
  float* S3    = ws + 524288;
  float* B1    = ws + 786432;
  float* B2    = ws + 1048576;
  float* A3o   = ws + 1310720;
  float* A12g  = ws + 1572864;       // 8192
  float* A13g  = ws + 1581056;       // 8192
  float* A23g  = ws + 1589248;       // 8192
  float* A123g = ws + 1597440;       // 256
  float* P     = ws + 1597696;       // 8388608 (32 MB)

  front_kernel<<<2560, 256, 0, stream>>>(x, W, bias, S1, S2, S3, P);
  mid_kernel<<<120, 256, 0, stream>>>(S1, S2, S3, W, B1, B2, A3o,
                                      A12g, A13g, A23g, A123g);
  back_kernel<<<2048, 256, 0, stream>>>(P, B1, B2, A3o, A12g, A13g, A23g,
                                        A123g, out);
}

// Round 10
// 108.175 us; speedup vs baseline: 1.0508x; 1.0508x over previous
//
#include <hip/hip_runtime.h>

// x: [8, 32, 32, 32, 32] fp32.  Flat = b*2^20 + i*32768 + j*1024 + k*32 + c
// W: [32, 256] row-major (o, 8 sections). Sections:
//   0:x 1:mean_i 2:mean_j 3:mean_k 4:mean_ij 5:mean_ik 6:mean_jk 7:mean_ijk
// out[b,i,j,k,o] = W0.x + B1[b,j,k,o] + B2[b,i,k,o] + A3[b,i,j,o]
//                + A12[b,k,o] + A13[b,j,o] + A23[b,i,o] + A123[b,o] + bias[o]
// R16: R4 base (107.4us best; reduce/mid verbatim). ONE lever: final_kernel
// phase overlap (T14 async-stage). Old final was phase-lockstep: stage burst
// -> sync (full queue drain) -> FMA -> epilogue table loads (latency fully
// exposed after FMA) -> store drain. New: 1024 blocks x 2 tiles; stage from
// prefetched regs; next tile's x prefetched during this tile's compute; all
// 17 table loads hoisted BEFORE the FMA loop and pre-combined into tb[4][4]
// (latency hides under FMA, +16 regs not +68). R15 lesson: P round-trip
// overlap costs more than it saves; R7: atomic grid barriers = 460us.

static __device__ __forceinline__ float4 f4add(float4 a, float4 b) {
  a.x += b.x; a.y += b.y; a.z += b.z; a.w += b.w; return a;
}

__global__ __launch_bounds__(256) void reduce_kernel(
    const float* __restrict__ x, float* __restrict__ S1,
    float* __restrict__ S2, float* __restrict__ S3) {
  const int t = threadIdx.x;
  if (blockIdx.x < 256) {
    // seg0: S1[b, j=a, k, c] = sum_i x[b,i,a,k,c]; thread owns floats 4t..4t+3
    const int b = blockIdx.x >> 5, a = blockIdx.x & 31;
    const float* base = x + ((size_t)b << 20) + a * 1024 + 4 * t;
    float4 acc = make_float4(0.f, 0.f, 0.f, 0.f);
    #pragma unroll
    for (int i = 0; i < 32; ++i) acc = f4add(acc, *(const float4*)(base + i * 32768));
    ((float4*)(S1 + (size_t)(b * 32 + a) * 1024))[t] = acc;
  } else {
    // segA: block (b, i=a): stream slab x[b,a,:,:,:] once -> S2 row + S3 row
    __shared__ float sT[8 * 1028];   // 8 j-rows of [k,c] (1024) + 4 pad
    const int idx = blockIdx.x - 256;
    const int b = idx >> 5, a = idx & 31;
    const float* slab = x + ((size_t)b << 20) + a * 32768;
    float4 accS2 = make_float4(0.f, 0.f, 0.f, 0.f);
    const int jl = t >> 5, cc = t & 31;      // S3 role: (j_loc, c)
    float* s3row = S3 + (size_t)(b * 32 + a) * 1024;

    for (int jt = 0; jt < 4; ++jt) {
      // load 8 KB tile (j = 8*jt .. +7), fully coalesced float4
      const float4* src4 = (const float4*)(slab + jt * 8192);
      #pragma unroll
      for (int m = 0; m < 8; ++m) {
        const int q = t + 256 * m;           // float4 idx in tile
        const float4 v = src4[q];
        float* p = sT + (q >> 8) * 1028 + 4 * (q & 255);
        p[0] = v.x; p[1] = v.y; p[2] = v.z; p[3] = v.w;
      }
      __syncthreads();
      // S2 accumulate: thread owns (k,c) quad at 4t
      #pragma unroll
      for (int j = 0; j < 8; ++j)
        accS2 = f4add(accS2, *(const float4*)(sT + j * 1028 + 4 * t));
      // S3: thread (jl, cc) sums over k; banks (4*jl + cc + 32k)%32: 2-way free
      float s3 = 0.f;
      #pragma unroll
      for (int k = 0; k < 32; ++k) s3 += sT[jl * 1028 + k * 32 + cc];
      s3row[jt * 256 + t] = s3;              // j = 8*jt + jl, coalesced
      __syncthreads();
    }
    ((float4*)(S2 + (size_t)(b * 32 + a) * 1024))[t] = accS2;
  }
}

// Merged: blocks 0..95 = three [8192x32]x[32x32] GEMMs (B1,B2,A3, scaled 1/32);
//         blocks 96..119 = second-level pools -> A12/A13/A23/A123 tables.
__global__ __launch_bounds__(256) void mid_kernel(
    const float* __restrict__ S1, const float* __restrict__ S2,
    const float* __restrict__ S3, const float* __restrict__ W,
    float* __restrict__ B1, float* __restrict__ B2, float* __restrict__ A3o,
    float* __restrict__ A12g, float* __restrict__ A13g,
    float* __restrict__ A23g, float* __restrict__ A123g,
    float* __restrict__ W0t) {
  __shared__ float smem[9472];
  const int t = threadIdx.x;
  if (blockIdx.x < 96) {
    float* xs = smem;            // [256][33]
    float* wt = smem + 8448;     // W section seg+1 transposed [c*32+o]
    const int seg = blockIdx.x >> 5;
    const int r0 = (blockIdx.x & 31) * 256;
    const float* src = (seg == 0) ? S1 : (seg == 1) ? S2 : S3;
    float* dst = (seg == 0) ? B1 : (seg == 1) ? B2 : A3o;

    const float4* sp4 = (const float4*)(src + (size_t)r0 * 32);
    #pragma unroll
    for (int m = 0; m < 8; ++m) {
      const int q = t + 256 * m;
      const float4 v = sp4[q];
      float* p = xs + (q >> 3) * 33 + 4 * (q & 7);
      p[0] = v.x; p[1] = v.y; p[2] = v.z; p[3] = v.w;
    }
    #pragma unroll
    for (int m = 0; m < 4; ++m) {
      const int e = t + 256 * m;
      wt[e] = W[(e & 31) * 256 + (seg + 1) * 32 + (e >> 5)];
    }
    if (blockIdx.x == 0) {
      #pragma unroll
      for (int m = 0; m < 4; ++m) {
        const int e = t + 256 * m;
        W0t[e] = W[(e & 31) * 256 + (e >> 5)];   // W0t[c*32+o]
      }
    }
    __syncthreads();

    float acc[32];
    #pragma unroll
    for (int o = 0; o < 32; ++o) acc[o] = 0.f;
    const float4* wt4 = (const float4*)wt;
    #pragma unroll
    for (int c = 0; c < 32; ++c) {
      const float xv = xs[t * 33 + c];
      #pragma unroll
      for (int o4 = 0; o4 < 8; ++o4) {
        const float4 w = wt4[c * 8 + o4];
        acc[o4 * 4 + 0] += xv * w.x;
        acc[o4 * 4 + 1] += xv * w.y;
        acc[o4 * 4 + 2] += xv * w.z;
        acc[o4 * 4 + 3] += xv * w.w;
      }
    }
    __syncthreads();
    #pragma unroll
    for (int o = 0; o < 32; ++o) xs[t * 33 + o] = acc[o] * (1.f / 32.f);
    __syncthreads();
    float* op = dst + (size_t)r0 * 32;
    #pragma unroll
    for (int m = 0; m < 32; ++m) {
      const int f = t + 256 * m;
      op[f] = xs[(f >> 5) * 33 + (f & 31)];
    }
  } else {
    // pool: blk = seg*8 + b
    const int blk = blockIdx.x - 96;
    const int seg = blk >> 3, b = blk & 7;
    float* sBuf  = smem;          // [32][32] second-level sums
    float* sW    = smem + 1024;   // section 4+seg transposed [c*32+o]
    float* sW7   = smem + 2048;   // section 7 transposed
    float* sS123 = smem + 3072;   // [32]
    const int sec = 4 + seg;

    #pragma unroll
    for (int m = 0; m < 4; ++m) {
      const int e = t + 256 * m, c = e >> 5, o = e & 31;
      sW[e] = W[o * 256 + sec * 32 + c];
      if (seg == 0) sW7[e] = W[o * 256 + 7 * 32 + c];
    }
    const float* Sb = ((seg == 2) ? S2 : S1) + (size_t)b * 32768;
    #pragma unroll
    for (int m = 0; m < 4; ++m) {
      const int e = t + 256 * m, a = e >> 5, c = e & 31;
      float s = 0.f;
      if (seg == 0) {            // S12[k=a,c] = sum_j S1[b,j,a,c]
        for (int j = 0; j < 32; ++j) s += Sb[j * 1024 + a * 32 + c];
      } else {                   // S13/S23[(j|i)=a,c] = sum_k
        for (int k = 0; k < 32; ++k) s += Sb[a * 1024 + k * 32 + c];
      }
      sBuf[e] = s;
    }
    __syncthreads();
    if (seg == 0 && t < 32) {
      float s = 0.f;
      for (int k = 0; k < 32; ++k) s += sBuf[k * 32 + t];
      sS123[t] = s;
    }
    __syncthreads();
    float* Ag = (seg == 0) ? A12g : (seg == 1) ? A13g : A23g;
    #pragma unroll
    for (int m = 0; m < 4; ++m) {
      const int e = t + 256 * m, a = e >> 5, o = e & 31;
      float s = 0.f;
      #pragma unroll
      for (int c = 0; c < 32; ++c) s += sW[c * 32 + o] * sBuf[a * 32 + c];
      Ag[b * 1024 + e] = s * (1.f / 1024.f);
    }
    if (seg == 0 && t < 32) {
      float s = 0.f;
      #pragma unroll
      for (int c = 0; c < 32; ++c) s += sW7[c * 32 + t] * sS123[c];
      A123g[b * 32 + t] = s * (1.f / 32768.f);
    }
  }
}

// 1024 blocks x 2 tiles (128 rows each), T14 pipelined: tile staged from
// prefetched regs; next tile's x loads fly under this tile's FMA; all table
// loads hoisted before FMA and pre-combined into tb[4][4].
// LDS 21KB; thread = (rg=t>>3: 4 rows, og=t&7: 4 outs).
__global__ __launch_bounds__(256) void final_kernel(
    const float* __restrict__ x, const float* __restrict__ W0t,
    const float* __restrict__ B1, const float* __restrict__ B2,
    const float* __restrict__ A3o, const float* __restrict__ A12g,
    const float* __restrict__ A13g, const float* __restrict__ A23g,
    const float* __restrict__ A123g, const float* __restrict__ bias,
    float* __restrict__ out) {
  __shared__ float xs[128 * 33];
  __shared__ float wt[1024];     // W0 transposed [c*32+o]
  const int t = threadIdx.x;
  const int rg = t >> 3, og = t & 7;
  const int lrow0 = 4 * rg;
  const int oo = og * 4;

  // prefetch tile 0 (blockIdx.x) and W0t into registers
  float4 xr0, xr1, xr2, xr3;
  {
    const float4* xp4 = (const float4*)(x + (size_t)blockIdx.x * 4096);
    xr0 = xp4[t]; xr1 = xp4[t + 256]; xr2 = xp4[t + 512]; xr3 = xp4[t + 768];
  }
  const float4 wr = ((const float4*)W0t)[t];

  for (int it = 0; it < 2; ++it) {
    const int tile = blockIdx.x + it * 1024;
    const size_t pos0 = (size_t)tile * 128;
    const size_t p0 = pos0 + lrow0;
    const int k0 = (int)(p0 & 31), j = (int)(p0 >> 5) & 31,
              i = (int)(p0 >> 10) & 31, b = (int)(p0 >> 15);

    // stage prefetched regs -> LDS
    {
      const float4 v0 = xr0, v1 = xr1, v2 = xr2, v3 = xr3;
      float* p;
      int q = t;
      p = xs + (q >> 3) * 33 + 4 * (q & 7);
      p[0] = v0.x; p[1] = v0.y; p[2] = v0.z; p[3] = v0.w;
      q = t + 256;
      p = xs + (q >> 3) * 33 + 4 * (q & 7);
      p[0] = v1.x; p[1] = v1.y; p[2] = v1.z; p[3] = v1.w;
      q = t + 512;
      p = xs + (q >> 3) * 33 + 4 * (q & 7);
      p[0] = v2.x; p[1] = v2.y; p[2] = v2.z; p[3] = v2.w;
      q = t + 768;
      p = xs + (q >> 3) * 33 + 4 * (q & 7);
      p[0] = v3.x; p[1] = v3.y; p[2] = v3.z; p[3] = v3.w;
    }
    if (it == 0) ((float4*)wt)[t] = wr;
    __syncthreads();

    // prefetch NEXT tile's x: loads fly under this tile's table-loads + FMA
    if (it == 0) {
      const float4* xp4 = (const float4*)(x + (pos0 + 131072) * 32);
      xr0 = xp4[t]; xr1 = xp4[t + 256]; xr2 = xp4[t + 512]; xr3 = xp4[t + 768];
    }

    // hoisted table loads, pre-combined (latency hides under FMA loop)
    const float4 va3  = *(const float4*)(A3o  + ((size_t)((b * 32 + i) * 32 + j)) * 32 + oo);
    const float4 va13 = *(const float4*)(A13g + (size_t)(b * 32 + j) * 32 + oo);
    const float4 va23 = *(const float4*)(A23g + (size_t)(b * 32 + i) * 32 + oo);
    const float4 va123= *(const float4*)(A123g + (size_t)b * 32 + oo);
    const float4 vbi  = *(const float4*)(bias + oo);
    float tb[4][4];
    #pragma unroll
    for (int r = 0; r < 4; ++r) {
      const int k = k0 + r;
      const float4 vb1 = *(const float4*)(B1 + ((size_t)((b * 32 + j) * 32 + k)) * 32 + oo);
      const float4 vb2 = *(const float4*)(B2 + ((size_t)((b * 32 + i) * 32 + k)) * 32 + oo);
      const float4 v12 = *(const float4*)(A12g + (size_t)(b * 32 + k) * 32 + oo);
      tb[r][0] = va3.x + va13.x + va23.x + va123.x + vbi.x + vb1.x + vb2.x + v12.x;
      tb[r][1] = va3.y + va13.y + va23.y + va123.y + vbi.y + vb1.y + vb2.y + v12.y;
      tb[r][2] = va3.z + va13.z + va23.z + va123.z + vbi.z + vb1.z + vb2.z + v12.z;
      tb[r][3] = va3.w + va13.w + va23.w + va123.w + vbi.w + vb1.w + vb2.w + v12.w;
    }

    float acc[4][4];
    #pragma unroll
    for (int r = 0; r < 4; ++r)
      #pragma unroll
      for (int u = 0; u < 4; ++u) acc[r][u] = 0.f;

    const float4* wt4 = (const float4*)wt;
    #pragma unroll
    for (int c = 0; c < 32; ++c) {
      const float4 w = wt4[c * 8 + og];
      #pragma unroll
      for (int r = 0; r < 4; ++r) {
        const float xv = xs[(lrow0 + r) * 33 + c];
        acc[r][0] += xv * w.x; acc[r][1] += xv * w.y;
        acc[r][2] += xv * w.z; acc[r][3] += xv * w.w;
      }
    }

    #pragma unroll
    for (int r = 0; r < 4; ++r) {
      *(float4*)(out + (p0 + r) * 32 + oo) = make_float4(
          acc[r][0] + tb[r][0], acc[r][1] + tb[r][1],
          acc[r][2] + tb[r][2], acc[r][3] + tb[r][3]);
    }
    __syncthreads();   // before next iteration overwrites xs
  }
}

extern "C" void kernel_launch(void* const* d_in, const int* in_sizes, int n_in,
                              void* d_out, int out_size, void* d_ws, size_t ws_size,
                              hipStream_t stream) {
  const float* x    = (const float*)d_in[0];
  const float* W    = (const float*)d_in[1];
  const float* bias = (const float*)d_in[2];
  float* out = (float*)d_out;
  float* ws  = (float*)d_ws;
  float* S1    = ws;                // 262144
  float* S2    = ws + 262144;
  float* S3    = ws + 524288;
  float* B1    = ws + 786432;
  float* B2    = ws + 1048576;
  float* A3o   = ws + 1310720;
  float* W0t   = ws + 1572864;      // 1024
  float* A12g  = ws + 1573888;      // 8192
  float* A13g  = ws + 1582080;      // 8192
  float* A23g  = ws + 1590272;      // 8192
  float* A123g = ws + 1598464;      // 256

  reduce_kernel<<<512, 256, 0, stream>>>(x, S1, S2, S3);
  mid_kernel<<<120, 256, 0, stream>>>(S1, S2, S3, W, B1, B2, A3o,
                                      A12g, A13g, A23g, A123g, W0t);
  final_kernel<<<1024, 256, 0, stream>>>(x, W0t, B1, B2, A3o, A12g, A13g,
                                         A23g, A123g, bias, out);
}

// Round 11
// 107.746 us; speedup vs baseline: 1.0550x; 1.0040x over previous
//
#include <hip/hip_runtime.h>

// x: [8, 32, 32, 32, 32] fp32.  Flat = b*2^20 + i*32768 + j*1024 + k*32 + c
// W: [32, 256] row-major (o, 8 sections). Sections:
//   0:x 1:mean_i 2:mean_j 3:mean_k 4:mean_ij 5:mean_ik 6:mean_jk 7:mean_ijk
// out[b,i,j,k,o] = W0.x + B1[b,j,k,o] + B2[b,i,k,o] + A3[b,i,j,o]
//                + A12[b,k,o] + A13[b,j,o] + A23[b,i,o] + A123[b,o] + bias[o]
// R17: R4 base (107.4 best; reduce/mid verbatim). Final: 64 rows/block,
// 4096 blocks (the tile-shrink axis is the only one that ever gained:
// 256->128 rows was +2.3us via occupancy 4->7; 64 rows -> 12.5KB LDS, 8
// blocks/CU wave-capped, half the per-block chain, finer tail). Keep R16's
// hoisted+precombined table epilogue. Ledger: overhead ~27us (R7 proves
// fill not timed), reduce ~28, mid ~7, final ~43 vs ~18 floor.

static __device__ __forceinline__ float4 f4add(float4 a, float4 b) {
  a.x += b.x; a.y += b.y; a.z += b.z; a.w += b.w; return a;
}

__global__ __launch_bounds__(256) void reduce_kernel(
    const float* __restrict__ x, float* __restrict__ S1,
    float* __restrict__ S2, float* __restrict__ S3) {
  const int t = threadIdx.x;
  if (blockIdx.x < 256) {
    // seg0: S1[b, j=a, k, c] = sum_i x[b,i,a,k,c]; thread owns floats 4t..4t+3
    const int b = blockIdx.x >> 5, a = blockIdx.x & 31;
    const float* base = x + ((size_t)b << 20) + a * 1024 + 4 * t;
    float4 acc = make_float4(0.f, 0.f, 0.f, 0.f);
    #pragma unroll
    for (int i = 0; i < 32; ++i) acc = f4add(acc, *(const float4*)(base + i * 32768));
    ((float4*)(S1 + (size_t)(b * 32 + a) * 1024))[t] = acc;
  } else {
    // segA: block (b, i=a): stream slab x[b,a,:,:,:] once -> S2 row + S3 row
    __shared__ float sT[8 * 1028];   // 8 j-rows of [k,c] (1024) + 4 pad
    const int idx = blockIdx.x - 256;
    const int b = idx >> 5, a = idx & 31;
    const float* slab = x + ((size_t)b << 20) + a * 32768;
    float4 accS2 = make_float4(0.f, 0.f, 0.f, 0.f);
    const int jl = t >> 5, cc = t & 31;      // S3 role: (j_loc, c)
    float* s3row = S3 + (size_t)(b * 32 + a) * 1024;

    for (int jt = 0; jt < 4; ++jt) {
      // load 8 KB tile (j = 8*jt .. +7), fully coalesced float4
      const float4* src4 = (const float4*)(slab + jt * 8192);
      #pragma unroll
      for (int m = 0; m < 8; ++m) {
        const int q = t + 256 * m;           // float4 idx in tile
        const float4 v = src4[q];
        float* p = sT + (q >> 8) * 1028 + 4 * (q & 255);
        p[0] = v.x; p[1] = v.y; p[2] = v.z; p[3] = v.w;
      }
      __syncthreads();
      // S2 accumulate: thread owns (k,c) quad at 4t
      #pragma unroll
      for (int j = 0; j < 8; ++j)
        accS2 = f4add(accS2, *(const float4*)(sT + j * 1028 + 4 * t));
      // S3: thread (jl, cc) sums over k; banks (4*jl + cc + 32k)%32: 2-way free
      float s3 = 0.f;
      #pragma unroll
      for (int k = 0; k < 32; ++k) s3 += sT[jl * 1028 + k * 32 + cc];
      s3row[jt * 256 + t] = s3;              // j = 8*jt + jl, coalesced
      __syncthreads();
    }
    ((float4*)(S2 + (size_t)(b * 32 + a) * 1024))[t] = accS2;
  }
}

// Merged: blocks 0..95 = three [8192x32]x[32x32] GEMMs (B1,B2,A3, scaled 1/32);
//         blocks 96..119 = second-level pools -> A12/A13/A23/A123 tables.
__global__ __launch_bounds__(256) void mid_kernel(
    const float* __restrict__ S1, const float* __restrict__ S2,
    const float* __restrict__ S3, const float* __restrict__ W,
    float* __restrict__ B1, float* __restrict__ B2, float* __restrict__ A3o,
    float* __restrict__ A12g, float* __restrict__ A13g,
    float* __restrict__ A23g, float* __restrict__ A123g,
    float* __restrict__ W0t) {
  __shared__ float smem[9472];
  const int t = threadIdx.x;
  if (blockIdx.x < 96) {
    float* xs = smem;            // [256][33]
    float* wt = smem + 8448;     // W section seg+1 transposed [c*32+o]
    const int seg = blockIdx.x >> 5;
    const int r0 = (blockIdx.x & 31) * 256;
    const float* src = (seg == 0) ? S1 : (seg == 1) ? S2 : S3;
    float* dst = (seg == 0) ? B1 : (seg == 1) ? B2 : A3o;

    const float4* sp4 = (const float4*)(src + (size_t)r0 * 32);
    #pragma unroll
    for (int m = 0; m < 8; ++m) {
      const int q = t + 256 * m;
      const float4 v = sp4[q];
      float* p = xs + (q >> 3) * 33 + 4 * (q & 7);
      p[0] = v.x; p[1] = v.y; p[2] = v.z; p[3] = v.w;
    }
    #pragma unroll
    for (int m = 0; m < 4; ++m) {
      const int e = t + 256 * m;
      wt[e] = W[(e & 31) * 256 + (seg + 1) * 32 + (e >> 5)];
    }
    if (blockIdx.x == 0) {
      #pragma unroll
      for (int m = 0; m < 4; ++m) {
        const int e = t + 256 * m;
        W0t[e] = W[(e & 31) * 256 + (e >> 5)];   // W0t[c*32+o]
      }
    }
    __syncthreads();

    float acc[32];
    #pragma unroll
    for (int o = 0; o < 32; ++o) acc[o] = 0.f;
    const float4* wt4 = (const float4*)wt;
    #pragma unroll
    for (int c = 0; c < 32; ++c) {
      const float xv = xs[t * 33 + c];
      #pragma unroll
      for (int o4 = 0; o4 < 8; ++o4) {
        const float4 w = wt4[c * 8 + o4];
        acc[o4 * 4 + 0] += xv * w.x;
        acc[o4 * 4 + 1] += xv * w.y;
        acc[o4 * 4 + 2] += xv * w.z;
        acc[o4 * 4 + 3] += xv * w.w;
      }
    }
    __syncthreads();
    #pragma unroll
    for (int o = 0; o < 32; ++o) xs[t * 33 + o] = acc[o] * (1.f / 32.f);
    __syncthreads();
    float* op = dst + (size_t)r0 * 32;
    #pragma unroll
    for (int m = 0; m < 32; ++m) {
      const int f = t + 256 * m;
      op[f] = xs[(f >> 5) * 33 + (f & 31)];
    }
  } else {
    // pool: blk = seg*8 + b
    const int blk = blockIdx.x - 96;
    const int seg = blk >> 3, b = blk & 7;
    float* sBuf  = smem;          // [32][32] second-level sums
    float* sW    = smem + 1024;   // section 4+seg transposed [c*32+o]
    float* sW7   = smem + 2048;   // section 7 transposed
    float* sS123 = smem + 3072;   // [32]
    const int sec = 4 + seg;

    #pragma unroll
    for (int m = 0; m < 4; ++m) {
      const int e = t + 256 * m, c = e >> 5, o = e & 31;
      sW[e] = W[o * 256 + sec * 32 + c];
      if (seg == 0) sW7[e] = W[o * 256 + 7 * 32 + c];
    }
    const float* Sb = ((seg == 2) ? S2 : S1) + (size_t)b * 32768;
    #pragma unroll
    for (int m = 0; m < 4; ++m) {
      const int e = t + 256 * m, a = e >> 5, c = e & 31;
      float s = 0.f;
      if (seg == 0) {            // S12[k=a,c] = sum_j S1[b,j,a,c]
        for (int j = 0; j < 32; ++j) s += Sb[j * 1024 + a * 32 + c];
      } else {                   // S13/S23[(j|i)=a,c] = sum_k
        for (int k = 0; k < 32; ++k) s += Sb[a * 1024 + k * 32 + c];
      }
      sBuf[e] = s;
    }
    __syncthreads();
    if (seg == 0 && t < 32) {
      float s = 0.f;
      for (int k = 0; k < 32; ++k) s += sBuf[k * 32 + t];
      sS123[t] = s;
    }
    __syncthreads();
    float* Ag = (seg == 0) ? A12g : (seg == 1) ? A13g : A23g;
    #pragma unroll
    for (int m = 0; m < 4; ++m) {
      const int e = t + 256 * m, a = e >> 5, o = e & 31;
      float s = 0.f;
      #pragma unroll
      for (int c = 0; c < 32; ++c) s += sW[c * 32 + o] * sBuf[a * 32 + c];
      Ag[b * 1024 + e] = s * (1.f / 1024.f);
    }
    if (seg == 0 && t < 32) {
      float s = 0.f;
      #pragma unroll
      for (int c = 0; c < 32; ++c) s += sW7[c * 32 + t] * sS123[c];
      A123g[b * 32 + t] = s * (1.f / 32768.f);
    }
  }
}

// 64 rows/block, 4096 blocks. LDS = 64*33 + 1024 floats = 12.5 KB ->
// 8 blocks/CU (wave-capped). Thread = (rg=t>>3: 2 rows, og=t&7: 4 outs).
// Tables hoisted before FMA and pre-combined into tb (R16 epilogue).
__global__ __launch_bounds__(256) void final_kernel(
    const float* __restrict__ x, const float* __restrict__ W0t,
    const float* __restrict__ B1, const float* __restrict__ B2,
    const float* __restrict__ A3o, const float* __restrict__ A12g,
    const float* __restrict__ A13g, const float* __restrict__ A23g,
    const float* __restrict__ A123g, const float* __restrict__ bias,
    float* __restrict__ out) {
  __shared__ float xs[64 * 33];
  __shared__ float wt[1024];     // W0 transposed [c*32+o]
  const int t = threadIdx.x;
  const size_t pos0 = (size_t)blockIdx.x * 64;

  const int rg = t >> 3, og = t & 7;
  const int lrow0 = 2 * rg;
  const size_t p0 = pos0 + lrow0;
  const int k0 = (int)(p0 & 31), j = (int)(p0 >> 5) & 31,
            i = (int)(p0 >> 10) & 31, b = (int)(p0 >> 15);
  const int oo = og * 4;

  // issue invariant + per-row table loads first; latency hides under
  // stage+sync+FMA (they commit into tb below).
  const float4 va3  = *(const float4*)(A3o  + ((size_t)((b * 32 + i) * 32 + j)) * 32 + oo);
  const float4 va13 = *(const float4*)(A13g + (size_t)(b * 32 + j) * 32 + oo);
  const float4 va23 = *(const float4*)(A23g + (size_t)(b * 32 + i) * 32 + oo);
  const float4 va123= *(const float4*)(A123g + (size_t)b * 32 + oo);
  const float4 vbi  = *(const float4*)(bias + oo);
  float4 vb1[2], vb2[2], v12[2];
  #pragma unroll
  for (int r = 0; r < 2; ++r) {
    const int k = k0 + r;
    vb1[r] = *(const float4*)(B1 + ((size_t)((b * 32 + j) * 32 + k)) * 32 + oo);
    vb2[r] = *(const float4*)(B2 + ((size_t)((b * 32 + i) * 32 + k)) * 32 + oo);
    v12[r] = *(const float4*)(A12g + (size_t)(b * 32 + k) * 32 + oo);
  }

  // stage x tile: 64 rows * 32c = 512 float4, 2 per thread
  const float4* xp4 = (const float4*)(x + pos0 * 32);
  #pragma unroll
  for (int m = 0; m < 2; ++m) {
    const int q = t + 256 * m;
    const float4 v = xp4[q];
    float* p = xs + (q >> 3) * 33 + 4 * (q & 7);
    p[0] = v.x; p[1] = v.y; p[2] = v.z; p[3] = v.w;
  }
  #pragma unroll
  for (int m = 0; m < 4; ++m) wt[t + 256 * m] = W0t[t + 256 * m];
  __syncthreads();

  // pre-combine tables (overlaps with other waves' LDS reads)
  float tb[2][4];
  #pragma unroll
  for (int r = 0; r < 2; ++r) {
    tb[r][0] = va3.x + va13.x + va23.x + va123.x + vbi.x + vb1[r].x + vb2[r].x + v12[r].x;
    tb[r][1] = va3.y + va13.y + va23.y + va123.y + vbi.y + vb1[r].y + vb2[r].y + v12[r].y;
    tb[r][2] = va3.z + va13.z + va23.z + va123.z + vbi.z + vb1[r].z + vb2[r].z + v12[r].z;
    tb[r][3] = va3.w + va13.w + va23.w + va123.w + vbi.w + vb1[r].w + vb2[r].w + v12[r].w;
  }

  float acc[2][4];
  #pragma unroll
  for (int r = 0; r < 2; ++r)
    #pragma unroll
    for (int u = 0; u < 4; ++u) acc[r][u] = 0.f;

  const float4* wt4 = (const float4*)wt;
  #pragma unroll
  for (int c = 0; c < 32; ++c) {
    const float4 w = wt4[c * 8 + og];
    #pragma unroll
    for (int r = 0; r < 2; ++r) {
      const float xv = xs[(lrow0 + r) * 33 + c];
      acc[r][0] += xv * w.x; acc[r][1] += xv * w.y;
      acc[r][2] += xv * w.z; acc[r][3] += xv * w.w;
    }
  }

  #pragma unroll
  for (int r = 0; r < 2; ++r) {
    *(float4*)(out + (p0 + r) * 32 + oo) = make_float4(
        acc[r][0] + tb[r][0], acc[r][1] + tb[r][1],
        acc[r][2] + tb[r][2], acc[r][3] + tb[r][3]);
  }
}

extern "C" void kernel_launch(void* const* d_in, const int* in_sizes, int n_in,
                              void* d_out, int out_size, void* d_ws, size_t ws_size,
                              hipStream_t stream) {
  const float* x    = (const float*)d_in[0];
  const float* W    = (const float*)d_in[1];
  const float* bias = (const float*)d_in[2];
  float* out = (float*)d_out;
  float* ws  = (float*)d_ws;
  float* S1    = ws;                // 262144
  float* S2    = ws + 262144;
  float* S3    = ws + 524288;
  float* B1    = ws + 786432;
  float* B2    = ws + 1048576;
  float* A3o   = ws + 1310720;
  float* W0t   = ws + 1572864;      // 1024
  float* A12g  = ws + 1573888;      // 8192
  float* A13g  = ws + 1582080;      // 8192
  float* A23g  = ws + 1590272;      // 8192
  float* A123g = ws + 1598464;      // 256

  reduce_kernel<<<512, 256, 0, stream>>>(x, S1, S2, S3);
  mid_kernel<<<120, 256, 0, stream>>>(S1, S2, S3, W, B1, B2, A3o,
                                      A12g, A13g, A23g, A123g, W0t);
  final_kernel<<<4096, 256, 0, stream>>>(x, W0t, B1, B2, A3o, A12g, A13g,
                                         A23g, A123g, bias, out);
}